// Round 9
// baseline (260.422 us; speedup 1.0000x reference)
//
#include <hip/hip_runtime.h>
#include <cstdint>

typedef __attribute__((ext_vector_type(8))) short short8;
typedef __attribute__((ext_vector_type(16))) float f32x16;

#define B_   32
#define IN_  2048
#define ID_  16
#define ON_  64
#define OD_  32
// weight strides (floats): o: 1048576, i: 512, d: 16, k: 1

__device__ __forceinline__ unsigned short f2bf(float f) {
    union { float f; uint32_t u; } c; c.f = f;
    uint32_t u = c.u;
    uint32_t r = (u + 0x7FFFu + ((u >> 16) & 1u)) >> 16;
    return (unsigned short)r;
}
__device__ __forceinline__ unsigned int pack2(float a, float b) {
    return (unsigned int)f2bf(a) | ((unsigned int)f2bf(b) << 16);
}

// ============================ FAST PATH =====================================
// ws layout (bytes):
//   wbf  : bf16 weight, MFMA frag order, uint4[(o*2048+i)*64+lane]    134,217,728
//   xbf  : bf16 x, MFMA frag order, uint4[i*64+lane]                    2,097,152
//   part : fp32 partials [64][(o*32+d)*32+b]   (TRANSPOSED layout)     16,777,216
//   L    : fp32 raw logits [i][o][b]                                   16,777,216
//   msum : fp32 [i][ {m[32], rinv[32]} ]                                  524,288
//   Ssum : fp32 [(o*32+d)*32+b]                                           262,144
//   v0, vsum : fp32 [o][b][d]                                             262,144 each
//
// Fragment symmetry: per-lane data {elem j at (lane&31, k=(lane>>5)*8+j)}
// serves as BOTH A-operand (m=lane&31) and B-operand (n=lane&31).
// mfma(af,bb) -> xhat[b][d];  mfma(bb,af) -> xhat^T[d][b] (b=lane&31 = lane-local!)

// ---- pack x -> frag layout: lane holds x[b=lane&31, i, k=half*8+j] ---------
__global__ __launch_bounds__(256) void xconv_k(
    const float* __restrict__ x, uint4* __restrict__ xbf)
{
    int t = threadIdx.x, lane = t & 63, wv = t >> 6;
    int i = blockIdx.x * 4 + wv;
    int b = lane & 31, half = lane >> 5;
    const float* g = x + ((size_t)b * IN_ + i) * ID_ + half * 8;
    float4 a = *(const float4*)g;
    float4 c = *(const float4*)(g + 4);
    uint4 p = { pack2(a.x, a.y), pack2(a.z, a.w), pack2(c.x, c.y), pack2(c.z, c.w) };
    xbf[(size_t)i * 64 + lane] = p;
}

// ---- pass0: read w fp32 direct->reg, emit wbf, swapped-MFMA S0^T partials --
// grid 1024 = 16 og (4 o) x 64 ic (32 i). block 256 = 4 waves x 1 o.
__global__ __launch_bounds__(256) void pass0_k2(
    const float* __restrict__ w, const uint4* __restrict__ xbf,
    uint4* __restrict__ wbf, float* __restrict__ part)
{
    int t = threadIdx.x, lane = t & 63, wv = t >> 6;
    int og = blockIdx.x & 15, ic = blockIdx.x >> 4;
    int o = og * 4 + wv;
    int b = lane & 31, half = lane >> 5;

    f32x16 acc = {};
    #pragma unroll 4
    for (int ii = 0; ii < 32; ++ii) {
        int i = ic * 32 + ii;
        union { uint4 u; short8 s; } af;
        af.u = xbf[(size_t)i * 64 + lane];
        const float* g = w + ((size_t)o * IN_ + i) * 512 + b * 16 + half * 8;
        float4 a = *(const float4*)g;
        float4 c = *(const float4*)(g + 4);
        union { uint4 u; short8 s; } bf;
        bf.u = (uint4){ pack2(a.x, a.y), pack2(a.z, a.w), pack2(c.x, c.y), pack2(c.z, c.w) };
        wbf[((size_t)o * IN_ + i) * 64 + lane] = bf.u;
        // swapped: acc = xhat^T[d][b], d = (r&3)+8*(r>>2)+4*half, b = lane&31
        acc = __builtin_amdgcn_mfma_f32_32x32x16_bf16(bf.s, af.s, acc, 0, 0, 0);
    }
    float* dst = part + (size_t)ic * 65536;
    #pragma unroll
    for (int r = 0; r < 16; ++r) {
        int d = (r & 3) + 8 * (r >> 2) + 4 * half;
        dst[(o * 32 + d) * 32 + b] = acc[r];    // 128 B coalesced per half
    }
}

// ---- raw logits via swapped-operand MFMA; dual-half coalesced L store ------
// grid 4096 = (ic = bx>>6) x (o = bx&63). block 256 = 4 waves x 8 i.
__global__ __launch_bounds__(256, 4) void logits_raw_k(
    const uint4* __restrict__ wbf, const uint4* __restrict__ xbf,
    const float* __restrict__ vin /*[o][b][d]*/, float* __restrict__ L)
{
    int t = threadIdx.x, lane = t & 63, wv = t >> 6;
    int o = blockIdx.x & 63, ic = blockIdx.x >> 6;
    int b = lane & 31, half = lane >> 5;

    // hoist v for this o: lane needs v[o][b=lane&31][d(r,half)] for r=0..15
    float vr[16];
    #pragma unroll
    for (int r = 0; r < 16; ++r) {
        int d = (r & 3) + 8 * (r >> 2) + 4 * half;
        vr[r] = vin[(size_t)o * (B_ * OD_) + b * 32 + d];
    }

    #pragma unroll
    for (int ii = 0; ii < 8; ii += 2) {
        int i0 = ic * 32 + wv * 8 + ii;
        float tot[2];
        #pragma unroll
        for (int q = 0; q < 2; ++q) {
            union { uint4 u; short8 s; } af, bb;
            af.u = xbf[(size_t)(i0 + q) * 64 + lane];
            bb.u = wbf[((size_t)o * IN_ + (i0 + q)) * 64 + lane];
            f32x16 z = {};
            f32x16 C2 = __builtin_amdgcn_mfma_f32_32x32x16_bf16(bb.s, af.s, z, 0, 0, 0);
            float p0 = C2[0] * vr[0], p1 = C2[1] * vr[1];
            float p2 = C2[2] * vr[2], p3 = C2[3] * vr[3];
            #pragma unroll
            for (int r = 4; r < 16; r += 4) {
                p0 += C2[r + 0] * vr[r + 0];
                p1 += C2[r + 1] * vr[r + 1];
                p2 += C2[r + 2] * vr[r + 2];
                p3 += C2[r + 3] * vr[r + 3];
            }
            float partial = (p0 + p1) + (p2 + p3);
            tot[q] = partial + __shfl_xor(partial, 32);  // both halves hold full sum
        }
        // half 0 stores i0's row, half 1 stores i1's row: full store BW
        int it = i0 + half;
        L[((size_t)it * 64 + o) * 32 + b] = half ? tot[1] : tot[0];
    }
}

// ---- per-(i,b) softmax stats over o: m and 1/sum (tiny output) -------------
// grid 512, block 256 = 4 waves, one i per wave.
__global__ __launch_bounds__(256) void msum_k(
    const float* __restrict__ L, float* __restrict__ msum /*[i][64]: m|rinv*/)
{
    __shared__ float sl[4][2048];
    int t = threadIdx.x, lane = t & 63, wv = t >> 6;
    int i = blockIdx.x * 4 + wv;
    const float4* src4 = reinterpret_cast<const float4*>(L + (size_t)i * 2048);
    float4* dst4 = reinterpret_cast<float4*>(sl[wv]);
    #pragma unroll
    for (int j = 0; j < 8; ++j) dst4[j * 64 + lane] = src4[j * 64 + lane];
    int b = lane & 31, half = lane >> 5;
    float m = -1e30f;
    #pragma unroll
    for (int o = 0; o < 32; ++o)
        m = fmaxf(m, sl[wv][(half * 32 + o) * 32 + b]);
    m = fmaxf(m, __shfl_xor(m, 32));
    float s = 0.0f;
    #pragma unroll
    for (int o = 0; o < 32; ++o)
        s += __expf(sl[wv][(half * 32 + o) * 32 + b] - m);
    s += __shfl_xor(s, 32);
    if (half == 0) {
        msum[(size_t)i * 64 + b]      = m;
        msum[(size_t)i * 64 + 32 + b] = 1.0f / s;
    }
}

// ---- accum: S^T partials = sum_i c * xhat^T; c applied in fp32 on output ---
// grid 1024 = 16 ic x 64 o. block 256 = 4 waves, wave owns 32 i's. acc = 16 regs.
__global__ __launch_bounds__(256, 4) void accum_k(
    const uint4* __restrict__ wbf, const uint4* __restrict__ xbf,
    const float* __restrict__ L, const float* __restrict__ msum,
    float* __restrict__ part)
{
    int t = threadIdx.x, lane = t & 63, wv = t >> 6;
    int o = blockIdx.x & 63, ic = blockIdx.x >> 6;
    int b = lane & 31, half = lane >> 5;
    int i0 = ic * 128 + wv * 32;

    f32x16 acc = {};
    #pragma unroll 8
    for (int ii = 0; ii < 32; ++ii) {
        int i = i0 + ii;
        union { uint4 u; short8 s; } af, bb;
        af.u = xbf[(size_t)i * 64 + lane];
        bb.u = wbf[((size_t)o * IN_ + i) * 64 + lane];
        f32x16 z = {};
        // independent of the c loads below -> deep ILP
        f32x16 C2 = __builtin_amdgcn_mfma_f32_32x32x16_bf16(bb.s, af.s, z, 0, 0, 0);
        float Lv   = L[((size_t)i * 64 + o) * 32 + b];
        float mv   = msum[(size_t)i * 64 + b];
        float rinv = msum[(size_t)i * 64 + 32 + b];
        float cl = __expf(Lv - mv) * rinv;        // lane-uniform per b: scalar scale
        #pragma unroll
        for (int r = 0; r < 16; ++r) acc[r] += cl * C2[r];
    }

    float* dst = part + (size_t)(ic * 4 + wv) * 65536;
    #pragma unroll
    for (int r = 0; r < 16; ++r) {
        int d = (r & 3) + 8 * (r >> 2) + 4 * half;
        dst[(o * 32 + d) * 32 + b] = acc[r];
    }
}

// ---- reduceA: sum 64 slices of part^T -> Ssum^T (streaming, coalesced) -----
// grid 256, block 256: flat 65536 elements.
__global__ __launch_bounds__(256) void reduceA_k(
    const float* __restrict__ part, float* __restrict__ Ssum)
{
    int idx = blockIdx.x * 256 + threadIdx.x;
    const float* p = part + idx;
    float s0 = 0, s1 = 0, s2 = 0, s3 = 0, s4 = 0, s5 = 0, s6 = 0, s7 = 0;
    #pragma unroll
    for (int s = 0; s < 64; s += 8) {
        s0 += p[(size_t)(s + 0) * 65536];
        s1 += p[(size_t)(s + 1) * 65536];
        s2 += p[(size_t)(s + 2) * 65536];
        s3 += p[(size_t)(s + 3) * 65536];
        s4 += p[(size_t)(s + 4) * 65536];
        s5 += p[(size_t)(s + 5) * 65536];
        s6 += p[(size_t)(s + 6) * 65536];
        s7 += p[(size_t)(s + 7) * 65536];
    }
    Ssum[idx] = (((s0 + s1) + (s2 + s3)) + ((s4 + s5) + (s6 + s7)));
}

// ---- reduceB: squash from Ssum^T; in-lane d-loop (no shuffles) -------------
// grid 32, block 64: lane b = lane&31, o = blockIdx.x*2 + (lane>>5).
__global__ __launch_bounds__(64) void reduceB_k(
    const float* __restrict__ Ssum, float scale,
    const float* __restrict__ addprev, float* __restrict__ outv, int out_bod)
{
    int lane = threadIdx.x & 63;
    int b = lane & 31;
    int o = blockIdx.x * 2 + (lane >> 5);
    float sv[32];
    float n2 = 0.0f;
    #pragma unroll
    for (int d = 0; d < 32; ++d) {
        float v = Ssum[(o * 32 + d) * 32 + b] * scale;
        sv[d] = v;
        n2 += v * v;
    }
    float norm = sqrtf(n2);
    float sc = n2 / ((1.0f + n2) * (norm + 1e-8f));
    if (out_bod) {
        float* dst = outv + ((size_t)b * 64 + o) * 32;
        #pragma unroll
        for (int d = 0; d < 32; ++d) dst[d] = sc * sv[d];
    } else {
        float* dst = outv + (size_t)o * 1024 + b * 32;
        const float* pv = addprev ? addprev + (size_t)o * 1024 + b * 32 : nullptr;
        #pragma unroll
        for (int d = 0; d < 32; ++d)
            dst[d] = sc * sv[d] + (pv ? pv[d] : 0.0f);
    }
}

// ============================ LEGACY PATH (round-1, proven) =================

__global__ __launch_bounds__(256, 4) void pass0_k(
    const float* __restrict__ x, const float* __restrict__ w, float* __restrict__ S)
{
    __shared__ __align__(16) unsigned short lw[16 * 512];
    __shared__ __align__(16) unsigned short lx[512];

    const int t = threadIdx.x, lane = t & 63, wv = t >> 6;
    const int bx = blockIdx.x;
    const int ic = bx & 255, og = bx >> 8;
    const int o0 = og * 16;
    const int d = lane & 31, half = lane >> 5;

    f32x16 acc[4] = {};

    for (int i = ic * 8; i < ic * 8 + 8; ++i) {
        #pragma unroll
        for (int r = 0; r < 4; ++r) {
            int cidx = r * 256 + t;
            int ol = cidx >> 6, j8 = cidx & 63;
            const float* g = w + (size_t)(o0 + ol) * 1048576 + (size_t)i * 512 + j8 * 8;
            float4 a = *(const float4*)g;
            float4 b2 = *(const float4*)(g + 4);
            uint4 val = { pack2(a.x, a.y), pack2(a.z, a.w), pack2(b2.x, b2.y), pack2(b2.z, b2.w) };
            *reinterpret_cast<uint4*>(&lw[ol * 512 + j8 * 8]) = val;
        }
        if (t < 128) {
            int b = t >> 2, kq = t & 3;
            float4 a = *(const float4*)(x + ((size_t)b * IN_ + i) * ID_ + kq * 4);
            uint2 val = { pack2(a.x, a.y), pack2(a.z, a.w) };
            *reinterpret_cast<uint2*>(&lx[b * 16 + kq * 4]) = val;
        }
        __syncthreads();

        short8 afr = *reinterpret_cast<const short8*>(&lx[(lane & 31) * 16 + half * 8]);
        #pragma unroll
        for (int oi = 0; oi < 4; ++oi) {
            int ol = wv * 4 + oi;
            short8 bfr = *reinterpret_cast<const short8*>(&lw[ol * 512 + d * 16 + half * 8]);
            acc[oi] = __builtin_amdgcn_mfma_f32_32x32x16_bf16(afr, bfr, acc[oi], 0, 0, 0);
        }
        __syncthreads();
    }

    #pragma unroll
    for (int oi = 0; oi < 4; ++oi) {
        int o = o0 + wv * 4 + oi;
        #pragma unroll
        for (int r = 0; r < 16; ++r) {
            int b = (r & 3) + 8 * (r >> 2) + 4 * half;
            atomicAdd(&S[((size_t)b * ON_ + o) * OD_ + d], acc[oi][r]);
        }
    }
}

__global__ __launch_bounds__(512, 2) void pass_route_k(
    const float* __restrict__ x, const float* __restrict__ w,
    const float* __restrict__ vin, float* __restrict__ S)
{
    __shared__ __align__(16) unsigned short lw[64 * 512];
    __shared__ __align__(16) unsigned short lx[512];
    __shared__ float blds[B_ * ON_];
    __shared__ float clds[B_ * ON_];

    const int t = threadIdx.x, lane = t & 63, wv = t >> 6;
    const int ic = blockIdx.x;
    const int d = lane & 31, half = lane >> 5;

    f32x16 acc[8] = {};

    for (int i = ic * 8; i < ic * 8 + 8; ++i) {
        #pragma unroll
        for (int r = 0; r < 8; ++r) {
            int cidx = r * 512 + t;
            int ol = cidx >> 6, j8 = cidx & 63;
            const float* g = w + (size_t)ol * 1048576 + (size_t)i * 512 + j8 * 8;
            float4 a = *(const float4*)g;
            float4 b2 = *(const float4*)(g + 4);
            uint4 val = { pack2(a.x, a.y), pack2(a.z, a.w), pack2(b2.x, b2.y), pack2(b2.z, b2.w) };
            *reinterpret_cast<uint4*>(&lw[ol * 512 + j8 * 8]) = val;
        }
        if (t < 128) {
            int b = t >> 2, kq = t & 3;
            float4 a = *(const float4*)(x + ((size_t)b * IN_ + i) * ID_ + kq * 4);
            uint2 val = { pack2(a.x, a.y), pack2(a.z, a.w) };
            *reinterpret_cast<uint2*>(&lx[b * 16 + kq * 4]) = val;
        }
        __syncthreads();

        short8 afr = *reinterpret_cast<const short8*>(&lx[(lane & 31) * 16 + half * 8]);
        short8 bfr[8];

        #pragma unroll
        for (int oi = 0; oi < 8; ++oi) {
            int o = wv * 8 + oi;
            bfr[oi] = *reinterpret_cast<const short8*>(&lw[o * 512 + d * 16 + half * 8]);
            f32x16 z = {};
            f32x16 C = __builtin_amdgcn_mfma_f32_32x32x16_bf16(afr, bfr[oi], z, 0, 0, 0);
            float bvp[16];
            #pragma unroll
            for (int r = 0; r < 16; ++r) {
                int b = (r & 3) + 8 * (r >> 2) + 4 * half;
                float vv = vin[((size_t)o * B_ + b) * OD_ + d];
                bvp[r] = C[r] * vv;
            }
            #pragma unroll
            for (int m = 1; m <= 16; m <<= 1) {
                #pragma unroll
                for (int r = 0; r < 16; ++r)
                    bvp[r] += __shfl_xor(bvp[r], m, 32);
            }
            if ((lane & 31) == 0) {
                #pragma unroll
                for (int r = 0; r < 16; ++r) {
                    int b = (r & 3) + 8 * (r >> 2) + 4 * half;
                    blds[b * ON_ + o] = bvp[r];
                }
            }
        }
        __syncthreads();

        {
            int o = t & 63, bq = t >> 6;
            #pragma unroll
            for (int j = 0; j < 4; ++j) {
                int b = bq + 8 * j;
                float v = blds[b * ON_ + o];
                float m = v;
                #pragma unroll
                for (int mm = 1; mm <= 32; mm <<= 1) m = fmaxf(m, __shfl_xor(m, mm, 64));
                float e = __expf(v - m);
                float ssum = e;
                #pragma unroll
                for (int mm = 1; mm <= 32; mm <<= 1) ssum += __shfl_xor(ssum, mm, 64);
                clds[b * ON_ + o] = e / ssum;
            }
        }
        __syncthreads();

        #pragma unroll
        for (int oi = 0; oi < 8; ++oi) {
            int o = wv * 8 + oi;
            f32x16 z = {};
            f32x16 C = __builtin_amdgcn_mfma_f32_32x32x16_bf16(afr, bfr[oi], z, 0, 0, 0);
            #pragma unroll
            for (int r = 0; r < 16; ++r) {
                int b = (r & 3) + 8 * (r >> 2) + 4 * half;
                acc[oi][r] += clds[b * ON_ + o] * C[r];
            }
        }
        __syncthreads();
    }

    #pragma unroll
    for (int oi = 0; oi < 8; ++oi) {
        int o = wv * 8 + oi;
        #pragma unroll
        for (int r = 0; r < 16; ++r) {
            int b = (r & 3) + 8 * (r >> 2) + 4 * half;
            atomicAdd(&S[((size_t)b * ON_ + o) * OD_ + d], acc[oi][r]);
        }
    }
}

__global__ __launch_bounds__(256) void squash_k(
    const float* __restrict__ S, const float* __restrict__ addprev,
    float* __restrict__ out, float scale, int out_bod)
{
    int t = threadIdx.x;
    int row = blockIdx.x * 8 + (t >> 5);
    int d = t & 31;
    int b = row >> 6, o = row & 63;
    float s = S[(size_t)row * OD_ + d] * scale;
    float n2 = s * s;
    #pragma unroll
    for (int mm = 1; mm <= 16; mm <<= 1) n2 += __shfl_xor(n2, mm, 32);
    float norm = sqrtf(n2);
    float sc = n2 / ((1.0f + n2) * (norm + 1e-8f));
    float v = sc * s;
    if (addprev) v += addprev[((size_t)o * B_ + b) * OD_ + d];
    if (out_bod)
        out[((size_t)b * ON_ + o) * OD_ + d] = v;
    else
        out[((size_t)o * B_ + b) * OD_ + d] = v;
}

// ============================ LAUNCHER ======================================

extern "C" void kernel_launch(void* const* d_in, const int* in_sizes, int n_in,
                              void* d_out, int out_size, void* d_ws, size_t ws_size,
                              hipStream_t stream) {
    (void)in_sizes; (void)n_in; (void)out_size;
    const float* x = (const float*)d_in[0];
    const float* w = (const float*)d_in[1];
    float* out = (float*)d_out;

    const size_t WBF_B  = 134217728;   // 64*2048*1024
    const size_t XBF_B  = 2097152;     // 2048*1024
    const size_t PART_B = 16777216;    // 64*65536*4
    const size_t L_B    = 16777216;    // 2048*2048*4
    const size_t MS_B   = 524288;      // 2048*64*4
    const size_t SS_B   = 262144;      // 65536*4
    const size_t V_B    = 262144;
    const size_t NEED   = WBF_B + XBF_B + PART_B + L_B + MS_B + SS_B + 2 * V_B;

    if (ws_size >= NEED) {
        uint8_t* wsb = (uint8_t*)d_ws;
        uint4* wbf  = (uint4*)wsb;
        uint4* xbf  = (uint4*)(wsb + WBF_B);
        float* part = (float*)(wsb + WBF_B + XBF_B);
        float* Lg   = (float*)(wsb + WBF_B + XBF_B + PART_B);
        float* ms   = (float*)(wsb + WBF_B + XBF_B + PART_B + L_B);
        float* Ss   = (float*)(wsb + WBF_B + XBF_B + PART_B + L_B + MS_B);
        float* v0   = (float*)(wsb + WBF_B + XBF_B + PART_B + L_B + MS_B + SS_B);
        float* vsum = (float*)(wsb + WBF_B + XBF_B + PART_B + L_B + MS_B + SS_B + V_B);

        xconv_k<<<512, 256, 0, stream>>>(x, xbf);
        pass0_k2<<<1024, 256, 0, stream>>>(w, xbf, wbf, part);
        reduceA_k<<<256, 256, 0, stream>>>(part, Ss);
        reduceB_k<<<32, 64, 0, stream>>>(Ss, 1.0f / 64.0f, nullptr, v0, 0);

        logits_raw_k<<<4096, 256, 0, stream>>>(wbf, xbf, v0, Lg);
        msum_k<<<512, 256, 0, stream>>>(Lg, ms);
        accum_k<<<1024, 256, 0, stream>>>(wbf, xbf, Lg, ms, part);
        reduceA_k<<<256, 256, 0, stream>>>(part, Ss);
        reduceB_k<<<32, 64, 0, stream>>>(Ss, 1.0f, v0, vsum, 0);

        logits_raw_k<<<4096, 256, 0, stream>>>(wbf, xbf, vsum, Lg);
        msum_k<<<512, 256, 0, stream>>>(Lg, ms);
        accum_k<<<1024, 256, 0, stream>>>(wbf, xbf, Lg, ms, part);
        reduceA_k<<<256, 256, 0, stream>>>(part, Ss);
        reduceB_k<<<32, 64, 0, stream>>>(Ss, 1.0f, nullptr, out, 1);
    } else {
        // legacy (round-1) path — needs only 768 KB of ws
        float* S    = (float*)d_ws;
        float* v0   = S + 65536;
        float* vsum = v0 + 65536;
        const size_t Sbytes = (size_t)65536 * sizeof(float);

        hipMemsetAsync(S, 0, Sbytes, stream);
        pass0_k<<<1024, 256, 0, stream>>>(x, w, S);
        squash_k<<<256, 256, 0, stream>>>(S, nullptr, v0, 1.0f / 64.0f, 0);

        hipMemsetAsync(S, 0, Sbytes, stream);
        pass_route_k<<<256, 512, 0, stream>>>(x, w, v0, S);
        squash_k<<<256, 256, 0, stream>>>(S, v0, vsum, 1.0f, 0);

        hipMemsetAsync(S, 0, Sbytes, stream);
        pass_route_k<<<256, 512, 0, stream>>>(x, w, vsum, S);
        squash_k<<<256, 256, 0, stream>>>(S, nullptr, out, 1.0f, 1);
    }
}

// Round 10
// 247.359 us; speedup vs baseline: 1.0528x; 1.0528x over previous
//
#include <hip/hip_runtime.h>
#include <cstdint>

typedef __attribute__((ext_vector_type(8))) short short8;
typedef __attribute__((ext_vector_type(16))) float f32x16;

#define B_   32
#define IN_  2048
#define ID_  16
#define ON_  64
#define OD_  32
// weight strides (floats): o: 1048576, i: 512, d: 16, k: 1

__device__ __forceinline__ unsigned short f2bf(float f) {
    union { float f; uint32_t u; } c; c.f = f;
    uint32_t u = c.u;
    uint32_t r = (u + 0x7FFFu + ((u >> 16) & 1u)) >> 16;
    return (unsigned short)r;
}
__device__ __forceinline__ unsigned int pack2(float a, float b) {
    return (unsigned int)f2bf(a) | ((unsigned int)f2bf(b) << 16);
}

// ============================ FAST PATH =====================================
// ws layout (bytes):
//   wbf  : bf16 weight, MFMA frag order, uint4[(o*2048+i)*64+lane]    134,217,728
//   xbf  : bf16 x, MFMA frag order, uint4[i*64+lane]                    2,097,152
//   part : fp32 partials [64][(o*32+d)*32+b]   (TRANSPOSED layout)     16,777,216
//   L    : fp32 raw logits [i][o][b]                                   16,777,216
//   msum : fp32 [i][ {m[32], rinv[32]} ]                                  524,288
//   Ssum : fp32 [(o*32+d)*32+b]                                           262,144
//   v0, vsum : fp32 [o][b][d]                                             262,144 each
//
// Fragment symmetry: per-lane data {elem j at (lane&31, k=(lane>>5)*8+j)}
// serves as BOTH A-operand (m=lane&31) and B-operand (n=lane&31).
// mfma(af,bb) -> xhat[b][d];  mfma(bb,af) -> xhat^T[d][b] (b=lane&31 = lane-local!)

// ---- pack x -> frag layout: lane holds x[b=lane&31, i, k=half*8+j] ---------
__global__ __launch_bounds__(256) void xconv_k(
    const float* __restrict__ x, uint4* __restrict__ xbf)
{
    int t = threadIdx.x, lane = t & 63, wv = t >> 6;
    int i = blockIdx.x * 4 + wv;
    int b = lane & 31, half = lane >> 5;
    const float* g = x + ((size_t)b * IN_ + i) * ID_ + half * 8;
    float4 a = *(const float4*)g;
    float4 c = *(const float4*)(g + 4);
    uint4 p = { pack2(a.x, a.y), pack2(a.z, a.w), pack2(c.x, c.y), pack2(c.z, c.w) };
    xbf[(size_t)i * 64 + lane] = p;
}

// ---- pass0: read w fp32 direct->reg, emit wbf, swapped-MFMA S0^T partials --
// grid 1024 = 16 og (4 o) x 64 ic (32 i). block 256 = 4 waves x 1 o.
__global__ __launch_bounds__(256) void pass0_k2(
    const float* __restrict__ w, const uint4* __restrict__ xbf,
    uint4* __restrict__ wbf, float* __restrict__ part)
{
    int t = threadIdx.x, lane = t & 63, wv = t >> 6;
    int og = blockIdx.x & 15, ic = blockIdx.x >> 4;
    int o = og * 4 + wv;
    int b = lane & 31, half = lane >> 5;

    f32x16 acc = {};
    #pragma unroll 4
    for (int ii = 0; ii < 32; ++ii) {
        int i = ic * 32 + ii;
        union { uint4 u; short8 s; } af;
        af.u = xbf[(size_t)i * 64 + lane];
        const float* g = w + ((size_t)o * IN_ + i) * 512 + b * 16 + half * 8;
        float4 a = *(const float4*)g;
        float4 c = *(const float4*)(g + 4);
        union { uint4 u; short8 s; } bf;
        bf.u = (uint4){ pack2(a.x, a.y), pack2(a.z, a.w), pack2(c.x, c.y), pack2(c.z, c.w) };
        wbf[((size_t)o * IN_ + i) * 64 + lane] = bf.u;
        // swapped: acc = xhat^T[d][b], d = (r&3)+8*(r>>2)+4*half, b = lane&31
        acc = __builtin_amdgcn_mfma_f32_32x32x16_bf16(bf.s, af.s, acc, 0, 0, 0);
    }
    float* dst = part + (size_t)ic * 65536;
    #pragma unroll
    for (int r = 0; r < 16; ++r) {
        int d = (r & 3) + 8 * (r >> 2) + 4 * half;
        dst[(o * 32 + d) * 32 + b] = acc[r];    // 128 B coalesced per half
    }
}

// ---- raw logits via swapped-operand MFMA; dual-half coalesced L store ------
// grid 4096 = (ic = bx>>6) x (o = bx&63). block 256 = 4 waves x 8 i.
__global__ __launch_bounds__(256, 4) void logits_raw_k(
    const uint4* __restrict__ wbf, const uint4* __restrict__ xbf,
    const float* __restrict__ vin /*[o][b][d]*/, float* __restrict__ L)
{
    int t = threadIdx.x, lane = t & 63, wv = t >> 6;
    int o = blockIdx.x & 63, ic = blockIdx.x >> 6;
    int b = lane & 31, half = lane >> 5;

    // hoist v for this o: lane needs v[o][b=lane&31][d(r,half)] for r=0..15
    float vr[16];
    #pragma unroll
    for (int r = 0; r < 16; ++r) {
        int d = (r & 3) + 8 * (r >> 2) + 4 * half;
        vr[r] = vin[(size_t)o * (B_ * OD_) + b * 32 + d];
    }

    #pragma unroll
    for (int ii = 0; ii < 8; ii += 2) {
        int i0 = ic * 32 + wv * 8 + ii;
        float tot[2];
        #pragma unroll
        for (int q = 0; q < 2; ++q) {
            union { uint4 u; short8 s; } af, bb;
            af.u = xbf[(size_t)(i0 + q) * 64 + lane];
            bb.u = wbf[((size_t)o * IN_ + (i0 + q)) * 64 + lane];
            f32x16 z = {};
            f32x16 C2 = __builtin_amdgcn_mfma_f32_32x32x16_bf16(bb.s, af.s, z, 0, 0, 0);
            float p0 = C2[0] * vr[0], p1 = C2[1] * vr[1];
            float p2 = C2[2] * vr[2], p3 = C2[3] * vr[3];
            #pragma unroll
            for (int r = 4; r < 16; r += 4) {
                p0 += C2[r + 0] * vr[r + 0];
                p1 += C2[r + 1] * vr[r + 1];
                p2 += C2[r + 2] * vr[r + 2];
                p3 += C2[r + 3] * vr[r + 3];
            }
            float partial = (p0 + p1) + (p2 + p3);
            tot[q] = partial + __shfl_xor(partial, 32);  // both halves hold full sum
        }
        // half 0 stores i0's row, half 1 stores i1's row: full store BW
        int it = i0 + half;
        L[((size_t)it * 64 + o) * 32 + b] = half ? tot[1] : tot[0];
    }
}

// ---- per-(i,b) softmax stats over o: m and 1/sum (tiny output) -------------
// grid 512, block 256 = 4 waves, one i per wave.
__global__ __launch_bounds__(256) void msum_k(
    const float* __restrict__ L, float* __restrict__ msum /*[i][64]: m|rinv*/)
{
    __shared__ float sl[4][2048];
    int t = threadIdx.x, lane = t & 63, wv = t >> 6;
    int i = blockIdx.x * 4 + wv;
    const float4* src4 = reinterpret_cast<const float4*>(L + (size_t)i * 2048);
    float4* dst4 = reinterpret_cast<float4*>(sl[wv]);
    #pragma unroll
    for (int j = 0; j < 8; ++j) dst4[j * 64 + lane] = src4[j * 64 + lane];
    int b = lane & 31, half = lane >> 5;
    float m = -1e30f;
    #pragma unroll
    for (int o = 0; o < 32; ++o)
        m = fmaxf(m, sl[wv][(half * 32 + o) * 32 + b]);
    m = fmaxf(m, __shfl_xor(m, 32));
    float s = 0.0f;
    #pragma unroll
    for (int o = 0; o < 32; ++o)
        s += __expf(sl[wv][(half * 32 + o) * 32 + b] - m);
    s += __shfl_xor(s, 32);
    if (half == 0) {
        msum[(size_t)i * 64 + b]      = m;
        msum[(size_t)i * 64 + 32 + b] = 1.0f / s;
    }
}

// ---- accum: S^T partials = sum_i c * xhat^T; c applied in fp32 on output ---
// grid 1024 = 16 ic x 64 o. block 256 = 4 waves, wave owns 32 i's. acc = 16 regs.
__global__ __launch_bounds__(256, 4) void accum_k(
    const uint4* __restrict__ wbf, const uint4* __restrict__ xbf,
    const float* __restrict__ L, const float* __restrict__ msum,
    float* __restrict__ part)
{
    int t = threadIdx.x, lane = t & 63, wv = t >> 6;
    int o = blockIdx.x & 63, ic = blockIdx.x >> 6;
    int b = lane & 31, half = lane >> 5;
    int i0 = ic * 128 + wv * 32;

    f32x16 acc = {};
    #pragma unroll 8
    for (int ii = 0; ii < 32; ++ii) {
        int i = i0 + ii;
        union { uint4 u; short8 s; } af, bb;
        af.u = xbf[(size_t)i * 64 + lane];
        bb.u = wbf[((size_t)o * IN_ + i) * 64 + lane];
        f32x16 z = {};
        // independent of the c loads below -> deep ILP
        f32x16 C2 = __builtin_amdgcn_mfma_f32_32x32x16_bf16(bb.s, af.s, z, 0, 0, 0);
        float Lv   = L[((size_t)i * 64 + o) * 32 + b];
        float mv   = msum[(size_t)i * 64 + b];
        float rinv = msum[(size_t)i * 64 + 32 + b];
        float cl = __expf(Lv - mv) * rinv;        // lane-uniform per b: scalar scale
        #pragma unroll
        for (int r = 0; r < 16; ++r) acc[r] += cl * C2[r];
    }

    float* dst = part + (size_t)(ic * 4 + wv) * 65536;
    #pragma unroll
    for (int r = 0; r < 16; ++r) {
        int d = (r & 3) + 8 * (r >> 2) + 4 * half;
        dst[(o * 32 + d) * 32 + b] = acc[r];
    }
}

// ---- reduceA: sum 64 slices of part^T -> Ssum^T (streaming, coalesced) -----
// grid 256, block 256: flat 65536 elements.
__global__ __launch_bounds__(256) void reduceA_k(
    const float* __restrict__ part, float* __restrict__ Ssum)
{
    int idx = blockIdx.x * 256 + threadIdx.x;
    const float* p = part + idx;
    float s0 = 0, s1 = 0, s2 = 0, s3 = 0, s4 = 0, s5 = 0, s6 = 0, s7 = 0;
    #pragma unroll
    for (int s = 0; s < 64; s += 8) {
        s0 += p[(size_t)(s + 0) * 65536];
        s1 += p[(size_t)(s + 1) * 65536];
        s2 += p[(size_t)(s + 2) * 65536];
        s3 += p[(size_t)(s + 3) * 65536];
        s4 += p[(size_t)(s + 4) * 65536];
        s5 += p[(size_t)(s + 5) * 65536];
        s6 += p[(size_t)(s + 6) * 65536];
        s7 += p[(size_t)(s + 7) * 65536];
    }
    Ssum[idx] = (((s0 + s1) + (s2 + s3)) + ((s4 + s5) + (s6 + s7)));
}

// ---- squashT: wide squash from Ssum^T (2048 rows x 32 lanes, shuffle n2) ---
// grid 256, block 256 = 8 rows/block; row = o*32 + b; lane d = t&31.
// Ssum is 256 KB -> L2-resident after reduceA; 65k threads hide the
// strided-load latency (this replaces the 2048-thread latency-bound reduceB).
__global__ __launch_bounds__(256) void squashT_k(
    const float* __restrict__ Ssum, float scale,
    const float* __restrict__ addprev /*[o][b][d]*/,
    float* __restrict__ outv, int out_bod)
{
    int t = threadIdx.x;
    int row = blockIdx.x * 8 + (t >> 5);   // row = o*32 + b
    int d = t & 31;
    int o = row >> 5, b = row & 31;
    float s = Ssum[(o * 32 + d) * 32 + b] * scale;
    float n2 = s * s;
    #pragma unroll
    for (int mm = 1; mm <= 16; mm <<= 1) n2 += __shfl_xor(n2, mm, 32);
    float norm = sqrtf(n2);
    float sc = n2 / ((1.0f + n2) * (norm + 1e-8f));
    float v = sc * s;
    if (addprev) v += addprev[(size_t)row * 32 + d];          // [o][b][d]
    if (out_bod)
        outv[((size_t)b * 64 + o) * 32 + d] = v;              // [b][o][d]
    else
        outv[(size_t)row * 32 + d] = v;                       // [o][b][d]
}

// ============================ LEGACY PATH (round-1, proven) =================

__global__ __launch_bounds__(256, 4) void pass0_k(
    const float* __restrict__ x, const float* __restrict__ w, float* __restrict__ S)
{
    __shared__ __align__(16) unsigned short lw[16 * 512];
    __shared__ __align__(16) unsigned short lx[512];

    const int t = threadIdx.x, lane = t & 63, wv = t >> 6;
    const int bx = blockIdx.x;
    const int ic = bx & 255, og = bx >> 8;
    const int o0 = og * 16;
    const int d = lane & 31, half = lane >> 5;

    f32x16 acc[4] = {};

    for (int i = ic * 8; i < ic * 8 + 8; ++i) {
        #pragma unroll
        for (int r = 0; r < 4; ++r) {
            int cidx = r * 256 + t;
            int ol = cidx >> 6, j8 = cidx & 63;
            const float* g = w + (size_t)(o0 + ol) * 1048576 + (size_t)i * 512 + j8 * 8;
            float4 a = *(const float4*)g;
            float4 b2 = *(const float4*)(g + 4);
            uint4 val = { pack2(a.x, a.y), pack2(a.z, a.w), pack2(b2.x, b2.y), pack2(b2.z, b2.w) };
            *reinterpret_cast<uint4*>(&lw[ol * 512 + j8 * 8]) = val;
        }
        if (t < 128) {
            int b = t >> 2, kq = t & 3;
            float4 a = *(const float4*)(x + ((size_t)b * IN_ + i) * ID_ + kq * 4);
            uint2 val = { pack2(a.x, a.y), pack2(a.z, a.w) };
            *reinterpret_cast<uint2*>(&lx[b * 16 + kq * 4]) = val;
        }
        __syncthreads();

        short8 afr = *reinterpret_cast<const short8*>(&lx[(lane & 31) * 16 + half * 8]);
        #pragma unroll
        for (int oi = 0; oi < 4; ++oi) {
            int ol = wv * 4 + oi;
            short8 bfr = *reinterpret_cast<const short8*>(&lw[ol * 512 + d * 16 + half * 8]);
            acc[oi] = __builtin_amdgcn_mfma_f32_32x32x16_bf16(afr, bfr, acc[oi], 0, 0, 0);
        }
        __syncthreads();
    }

    #pragma unroll
    for (int oi = 0; oi < 4; ++oi) {
        int o = o0 + wv * 4 + oi;
        #pragma unroll
        for (int r = 0; r < 16; ++r) {
            int b = (r & 3) + 8 * (r >> 2) + 4 * half;
            atomicAdd(&S[((size_t)b * ON_ + o) * OD_ + d], acc[oi][r]);
        }
    }
}

__global__ __launch_bounds__(512, 2) void pass_route_k(
    const float* __restrict__ x, const float* __restrict__ w,
    const float* __restrict__ vin, float* __restrict__ S)
{
    __shared__ __align__(16) unsigned short lw[64 * 512];
    __shared__ __align__(16) unsigned short lx[512];
    __shared__ float blds[B_ * ON_];
    __shared__ float clds[B_ * ON_];

    const int t = threadIdx.x, lane = t & 63, wv = t >> 6;
    const int ic = blockIdx.x;
    const int d = lane & 31, half = lane >> 5;

    f32x16 acc[8] = {};

    for (int i = ic * 8; i < ic * 8 + 8; ++i) {
        #pragma unroll
        for (int r = 0; r < 8; ++r) {
            int cidx = r * 512 + t;
            int ol = cidx >> 6, j8 = cidx & 63;
            const float* g = w + (size_t)ol * 1048576 + (size_t)i * 512 + j8 * 8;
            float4 a = *(const float4*)g;
            float4 b2 = *(const float4*)(g + 4);
            uint4 val = { pack2(a.x, a.y), pack2(a.z, a.w), pack2(b2.x, b2.y), pack2(b2.z, b2.w) };
            *reinterpret_cast<uint4*>(&lw[ol * 512 + j8 * 8]) = val;
        }
        if (t < 128) {
            int b = t >> 2, kq = t & 3;
            float4 a = *(const float4*)(x + ((size_t)b * IN_ + i) * ID_ + kq * 4);
            uint2 val = { pack2(a.x, a.y), pack2(a.z, a.w) };
            *reinterpret_cast<uint2*>(&lx[b * 16 + kq * 4]) = val;
        }
        __syncthreads();

        short8 afr = *reinterpret_cast<const short8*>(&lx[(lane & 31) * 16 + half * 8]);
        short8 bfr[8];

        #pragma unroll
        for (int oi = 0; oi < 8; ++oi) {
            int o = wv * 8 + oi;
            bfr[oi] = *reinterpret_cast<const short8*>(&lw[o * 512 + d * 16 + half * 8]);
            f32x16 z = {};
            f32x16 C = __builtin_amdgcn_mfma_f32_32x32x16_bf16(afr, bfr[oi], z, 0, 0, 0);
            float bvp[16];
            #pragma unroll
            for (int r = 0; r < 16; ++r) {
                int b = (r & 3) + 8 * (r >> 2) + 4 * half;
                float vv = vin[((size_t)o * B_ + b) * OD_ + d];
                bvp[r] = C[r] * vv;
            }
            #pragma unroll
            for (int m = 1; m <= 16; m <<= 1) {
                #pragma unroll
                for (int r = 0; r < 16; ++r)
                    bvp[r] += __shfl_xor(bvp[r], m, 32);
            }
            if ((lane & 31) == 0) {
                #pragma unroll
                for (int r = 0; r < 16; ++r) {
                    int b = (r & 3) + 8 * (r >> 2) + 4 * half;
                    blds[b * ON_ + o] = bvp[r];
                }
            }
        }
        __syncthreads();

        {
            int o = t & 63, bq = t >> 6;
            #pragma unroll
            for (int j = 0; j < 4; ++j) {
                int b = bq + 8 * j;
                float v = blds[b * ON_ + o];
                float m = v;
                #pragma unroll
                for (int mm = 1; mm <= 32; mm <<= 1) m = fmaxf(m, __shfl_xor(m, mm, 64));
                float e = __expf(v - m);
                float ssum = e;
                #pragma unroll
                for (int mm = 1; mm <= 32; mm <<= 1) ssum += __shfl_xor(ssum, mm, 64);
                clds[b * ON_ + o] = e / ssum;
            }
        }
        __syncthreads();

        #pragma unroll
        for (int oi = 0; oi < 8; ++oi) {
            int o = wv * 8 + oi;
            f32x16 z = {};
            f32x16 C = __builtin_amdgcn_mfma_f32_32x32x16_bf16(afr, bfr[oi], z, 0, 0, 0);
            #pragma unroll
            for (int r = 0; r < 16; ++r) {
                int b = (r & 3) + 8 * (r >> 2) + 4 * half;
                acc[oi][r] += clds[b * ON_ + o] * C[r];
            }
        }
        __syncthreads();
    }

    #pragma unroll
    for (int oi = 0; oi < 8; ++oi) {
        int o = wv * 8 + oi;
        #pragma unroll
        for (int r = 0; r < 16; ++r) {
            int b = (r & 3) + 8 * (r >> 2) + 4 * half;
            atomicAdd(&S[((size_t)b * ON_ + o) * OD_ + d], acc[oi][r]);
        }
    }
}

__global__ __launch_bounds__(256) void squash_k(
    const float* __restrict__ S, const float* __restrict__ addprev,
    float* __restrict__ out, float scale, int out_bod)
{
    int t = threadIdx.x;
    int row = blockIdx.x * 8 + (t >> 5);
    int d = t & 31;
    int b = row >> 6, o = row & 63;
    float s = S[(size_t)row * OD_ + d] * scale;
    float n2 = s * s;
    #pragma unroll
    for (int mm = 1; mm <= 16; mm <<= 1) n2 += __shfl_xor(n2, mm, 32);
    float norm = sqrtf(n2);
    float sc = n2 / ((1.0f + n2) * (norm + 1e-8f));
    float v = sc * s;
    if (addprev) v += addprev[((size_t)o * B_ + b) * OD_ + d];
    if (out_bod)
        out[((size_t)b * ON_ + o) * OD_ + d] = v;
    else
        out[((size_t)o * B_ + b) * OD_ + d] = v;
}

// ============================ LAUNCHER ======================================

extern "C" void kernel_launch(void* const* d_in, const int* in_sizes, int n_in,
                              void* d_out, int out_size, void* d_ws, size_t ws_size,
                              hipStream_t stream) {
    (void)in_sizes; (void)n_in; (void)out_size;
    const float* x = (const float*)d_in[0];
    const float* w = (const float*)d_in[1];
    float* out = (float*)d_out;

    const size_t WBF_B  = 134217728;   // 64*2048*1024
    const size_t XBF_B  = 2097152;     // 2048*1024
    const size_t PART_B = 16777216;    // 64*65536*4
    const size_t L_B    = 16777216;    // 2048*2048*4
    const size_t MS_B   = 524288;      // 2048*64*4
    const size_t SS_B   = 262144;      // 65536*4
    const size_t V_B    = 262144;
    const size_t NEED   = WBF_B + XBF_B + PART_B + L_B + MS_B + SS_B + 2 * V_B;

    if (ws_size >= NEED) {
        uint8_t* wsb = (uint8_t*)d_ws;
        uint4* wbf  = (uint4*)wsb;
        uint4* xbf  = (uint4*)(wsb + WBF_B);
        float* part = (float*)(wsb + WBF_B + XBF_B);
        float* Lg   = (float*)(wsb + WBF_B + XBF_B + PART_B);
        float* ms   = (float*)(wsb + WBF_B + XBF_B + PART_B + L_B);
        float* Ss   = (float*)(wsb + WBF_B + XBF_B + PART_B + L_B + MS_B);
        float* v0   = (float*)(wsb + WBF_B + XBF_B + PART_B + L_B + MS_B + SS_B);
        float* vsum = (float*)(wsb + WBF_B + XBF_B + PART_B + L_B + MS_B + SS_B + V_B);

        xconv_k<<<512, 256, 0, stream>>>(x, xbf);
        pass0_k2<<<1024, 256, 0, stream>>>(w, xbf, wbf, part);
        reduceA_k<<<256, 256, 0, stream>>>(part, Ss);
        squashT_k<<<256, 256, 0, stream>>>(Ss, 1.0f / 64.0f, nullptr, v0, 0);

        logits_raw_k<<<4096, 256, 0, stream>>>(wbf, xbf, v0, Lg);
        msum_k<<<512, 256, 0, stream>>>(Lg, ms);
        accum_k<<<1024, 256, 0, stream>>>(wbf, xbf, Lg, ms, part);
        reduceA_k<<<256, 256, 0, stream>>>(part, Ss);
        squashT_k<<<256, 256, 0, stream>>>(Ss, 1.0f, v0, vsum, 0);

        logits_raw_k<<<4096, 256, 0, stream>>>(wbf, xbf, vsum, Lg);
        msum_k<<<512, 256, 0, stream>>>(Lg, ms);
        accum_k<<<1024, 256, 0, stream>>>(wbf, xbf, Lg, ms, part);
        reduceA_k<<<256, 256, 0, stream>>>(part, Ss);
        squashT_k<<<256, 256, 0, stream>>>(Ss, 1.0f, nullptr, out, 1);
    } else {
        // legacy (round-1) path — needs only 768 KB of ws
        float* S    = (float*)d_ws;
        float* v0   = S + 65536;
        float* vsum = v0 + 65536;
        const size_t Sbytes = (size_t)65536 * sizeof(float);

        hipMemsetAsync(S, 0, Sbytes, stream);
        pass0_k<<<1024, 256, 0, stream>>>(x, w, S);
        squash_k<<<256, 256, 0, stream>>>(S, nullptr, v0, 1.0f / 64.0f, 0);

        hipMemsetAsync(S, 0, Sbytes, stream);
        pass_route_k<<<256, 512, 0, stream>>>(x, w, v0, S);
        squash_k<<<256, 256, 0, stream>>>(S, v0, vsum, 1.0f, 0);

        hipMemsetAsync(S, 0, Sbytes, stream);
        pass_route_k<<<256, 512, 0, stream>>>(x, w, vsum, S);
        squash_k<<<256, 256, 0, stream>>>(S, nullptr, out, 1.0f, 1);
    }
}

// Round 11
// 246.790 us; speedup vs baseline: 1.0552x; 1.0023x over previous
//
#include <hip/hip_runtime.h>
#include <cstdint>

typedef __attribute__((ext_vector_type(8))) short short8;
typedef __attribute__((ext_vector_type(16))) float f32x16;

#define B_   32
#define IN_  2048
#define ID_  16
#define ON_  64
#define OD_  32
// weight strides (floats): o: 1048576, i: 512, d: 16, k: 1

__device__ __forceinline__ unsigned short f2bf(float f) {
    union { float f; uint32_t u; } c; c.f = f;
    uint32_t u = c.u;
    uint32_t r = (u + 0x7FFFu + ((u >> 16) & 1u)) >> 16;
    return (unsigned short)r;
}
__device__ __forceinline__ unsigned int pack2(float a, float b) {
    return (unsigned int)f2bf(a) | ((unsigned int)f2bf(b) << 16);
}

// ============================ FAST PATH =====================================
// ws layout (bytes):
//   wbf  : bf16 weight, MFMA frag order, uint4[(o*2048+i)*64+lane]    134,217,728
//   xbf  : bf16 x, MFMA frag order, uint4[i*64+lane]                    2,097,152
//   part : fp32 partials [64][(o*32+d)*32+b]   (TRANSPOSED layout)     16,777,216
//   L    : fp32 raw logits [i][o][b]                                   16,777,216
//   msum : float2 [i][b] {m, rinv}                                        524,288
//   v0, vsum : fp32 [o][b][d]                                             262,144 each
//
// Fragment symmetry: per-lane data {elem j at (lane&31, k=(lane>>5)*8+j)}
// serves as BOTH A-operand (m=lane&31) and B-operand (n=lane&31).
// mfma(af,bb) -> xhat[b][d];  mfma(bb,af) -> xhat^T[d][b] (b=lane&31 = lane-local!)

// ---- pack x -> frag layout: lane holds x[b=lane&31, i, k=half*8+j] ---------
__global__ __launch_bounds__(256) void xconv_k(
    const float* __restrict__ x, uint4* __restrict__ xbf)
{
    int t = threadIdx.x, lane = t & 63, wv = t >> 6;
    int i = blockIdx.x * 4 + wv;
    int b = lane & 31, half = lane >> 5;
    const float* g = x + ((size_t)b * IN_ + i) * ID_ + half * 8;
    float4 a = *(const float4*)g;
    float4 c = *(const float4*)(g + 4);
    uint4 p = { pack2(a.x, a.y), pack2(a.z, a.w), pack2(c.x, c.y), pack2(c.z, c.w) };
    xbf[(size_t)i * 64 + lane] = p;
}

// ---- pass0: read w fp32 direct->reg, emit wbf, swapped-MFMA S0^T partials --
// grid 1024 = 16 og (4 o) x 64 ic (32 i). block 256 = 4 waves x 1 o.
__global__ __launch_bounds__(256) void pass0_k2(
    const float* __restrict__ w, const uint4* __restrict__ xbf,
    uint4* __restrict__ wbf, float* __restrict__ part)
{
    int t = threadIdx.x, lane = t & 63, wv = t >> 6;
    int og = blockIdx.x & 15, ic = blockIdx.x >> 4;
    int o = og * 4 + wv;
    int b = lane & 31, half = lane >> 5;

    f32x16 acc = {};
    #pragma unroll 4
    for (int ii = 0; ii < 32; ++ii) {
        int i = ic * 32 + ii;
        union { uint4 u; short8 s; } af;
        af.u = xbf[(size_t)i * 64 + lane];
        const float* g = w + ((size_t)o * IN_ + i) * 512 + b * 16 + half * 8;
        float4 a = *(const float4*)g;
        float4 c = *(const float4*)(g + 4);
        union { uint4 u; short8 s; } bf;
        bf.u = (uint4){ pack2(a.x, a.y), pack2(a.z, a.w), pack2(c.x, c.y), pack2(c.z, c.w) };
        wbf[((size_t)o * IN_ + i) * 64 + lane] = bf.u;
        // swapped: acc = xhat^T[d][b], d = (r&3)+8*(r>>2)+4*half, b = lane&31
        acc = __builtin_amdgcn_mfma_f32_32x32x16_bf16(bf.s, af.s, acc, 0, 0, 0);
    }
    float* dst = part + (size_t)ic * 65536;
    #pragma unroll
    for (int r = 0; r < 16; ++r) {
        int d = (r & 3) + 8 * (r >> 2) + 4 * half;
        dst[(o * 32 + d) * 32 + b] = acc[r];    // 128 B coalesced per half
    }
}

// ---- raw logits via swapped-operand MFMA; dual-half coalesced L store ------
// grid 4096 = (ic = bx>>6) x (o = bx&63). block 256 = 4 waves x 8 i.
__global__ __launch_bounds__(256, 4) void logits_raw_k(
    const uint4* __restrict__ wbf, const uint4* __restrict__ xbf,
    const float* __restrict__ vin /*[o][b][d]*/, float* __restrict__ L)
{
    int t = threadIdx.x, lane = t & 63, wv = t >> 6;
    int o = blockIdx.x & 63, ic = blockIdx.x >> 6;
    int b = lane & 31, half = lane >> 5;

    // hoist v for this o: lane needs v[o][b=lane&31][d(r,half)] for r=0..15
    float vr[16];
    #pragma unroll
    for (int r = 0; r < 16; ++r) {
        int d = (r & 3) + 8 * (r >> 2) + 4 * half;
        vr[r] = vin[(size_t)o * (B_ * OD_) + b * 32 + d];
    }

    #pragma unroll
    for (int ii = 0; ii < 8; ii += 2) {
        int i0 = ic * 32 + wv * 8 + ii;
        float tot[2];
        #pragma unroll
        for (int q = 0; q < 2; ++q) {
            union { uint4 u; short8 s; } af, bb;
            af.u = xbf[(size_t)(i0 + q) * 64 + lane];
            bb.u = wbf[((size_t)o * IN_ + (i0 + q)) * 64 + lane];
            f32x16 z = {};
            f32x16 C2 = __builtin_amdgcn_mfma_f32_32x32x16_bf16(bb.s, af.s, z, 0, 0, 0);
            float p0 = C2[0] * vr[0], p1 = C2[1] * vr[1];
            float p2 = C2[2] * vr[2], p3 = C2[3] * vr[3];
            #pragma unroll
            for (int r = 4; r < 16; r += 4) {
                p0 += C2[r + 0] * vr[r + 0];
                p1 += C2[r + 1] * vr[r + 1];
                p2 += C2[r + 2] * vr[r + 2];
                p3 += C2[r + 3] * vr[r + 3];
            }
            float partial = (p0 + p1) + (p2 + p3);
            tot[q] = partial + __shfl_xor(partial, 32);  // both halves hold full sum
        }
        // half 0 stores i0's row, half 1 stores i1's row: full store BW
        int it = i0 + half;
        L[((size_t)it * 64 + o) * 32 + b] = half ? tot[1] : tot[0];
    }
}

// ---- per-(i,b) softmax stats over o: {m, 1/sum} as float2 ------------------
// grid 512, block 256 = 4 waves, one i per wave.
__global__ __launch_bounds__(256) void msum_k(
    const float* __restrict__ L, float2* __restrict__ msum /*[i][b]{m,rinv}*/)
{
    __shared__ float sl[4][2048];
    int t = threadIdx.x, lane = t & 63, wv = t >> 6;
    int i = blockIdx.x * 4 + wv;
    const float4* src4 = reinterpret_cast<const float4*>(L + (size_t)i * 2048);
    float4* dst4 = reinterpret_cast<float4*>(sl[wv]);
    #pragma unroll
    for (int j = 0; j < 8; ++j) dst4[j * 64 + lane] = src4[j * 64 + lane];
    int b = lane & 31, half = lane >> 5;
    float m = -1e30f;
    #pragma unroll
    for (int o = 0; o < 32; ++o)
        m = fmaxf(m, sl[wv][(half * 32 + o) * 32 + b]);
    m = fmaxf(m, __shfl_xor(m, 32));
    float s = 0.0f;
    #pragma unroll
    for (int o = 0; o < 32; ++o)
        s += __expf(sl[wv][(half * 32 + o) * 32 + b] - m);
    s += __shfl_xor(s, 32);
    if (half == 0) {
        float2 mr = { m, 1.0f / s };
        msum[(size_t)i * 32 + b] = mr;
    }
}

// ---- accum: S^T partials = sum_i c * xhat^T; c applied in fp32 on output ---
// grid 1024 = 16 ic x 64 o. block 256 = 4 waves, wave owns 32 i's. acc = 16 regs.
__global__ __launch_bounds__(256, 4) void accum_k(
    const uint4* __restrict__ wbf, const uint4* __restrict__ xbf,
    const float* __restrict__ L, const float2* __restrict__ msum,
    float* __restrict__ part)
{
    int t = threadIdx.x, lane = t & 63, wv = t >> 6;
    int o = blockIdx.x & 63, ic = blockIdx.x >> 6;
    int b = lane & 31, half = lane >> 5;
    int i0 = ic * 128 + wv * 32;

    f32x16 acc = {};
    #pragma unroll 8
    for (int ii = 0; ii < 32; ++ii) {
        int i = i0 + ii;
        union { uint4 u; short8 s; } af, bb;
        af.u = xbf[(size_t)i * 64 + lane];
        bb.u = wbf[((size_t)o * IN_ + i) * 64 + lane];
        f32x16 z = {};
        // independent of the c loads below -> deep ILP
        f32x16 C2 = __builtin_amdgcn_mfma_f32_32x32x16_bf16(bb.s, af.s, z, 0, 0, 0);
        float Lv  = L[((size_t)i * 64 + o) * 32 + b];
        float2 mr = msum[(size_t)i * 32 + b];
        float cl = __expf(Lv - mr.x) * mr.y;      // lane-uniform per b: scalar scale
        #pragma unroll
        for (int r = 0; r < 16; ++r) acc[r] += cl * C2[r];
    }

    float* dst = part + (size_t)(ic * 4 + wv) * 65536;
    #pragma unroll
    for (int r = 0; r < 16; ++r) {
        int d = (r & 3) + 8 * (r >> 2) + 4 * half;
        dst[(o * 32 + d) * 32 + b] = acc[r];
    }
}

// ---- fused reduce+squash: slice-sum -> n2 over d -> squash -> write --------
// grid 64 (one o per block), block 1024. Thread t: d = t>>5, b = t&31.
// Replaces reduceA_k + squashT_k (saves a launch + the Ssum round trip).
__global__ __launch_bounds__(1024) void reduce_squash_fused_k(
    const float* __restrict__ part, float scale,
    const float* __restrict__ addprev /*[o][b][d]*/,
    float* __restrict__ outv, int out_bod)
{
    __shared__ float svl[32 * 33];   // [d*33+b], pad 33 -> conflict-free
    __shared__ float scl[32];        // squash scale per b
    int t = threadIdx.x;
    int o = blockIdx.x;
    int d = t >> 5, b = t & 31;

    const float* p = part + (size_t)o * 1024 + t;   // idx = (o*32+d)*32+b
    float s0 = 0, s1 = 0, s2 = 0, s3 = 0, s4 = 0, s5 = 0, s6 = 0, s7 = 0;
    #pragma unroll
    for (int s = 0; s < 64; s += 8) {
        s0 += p[(size_t)(s + 0) * 65536];
        s1 += p[(size_t)(s + 1) * 65536];
        s2 += p[(size_t)(s + 2) * 65536];
        s3 += p[(size_t)(s + 3) * 65536];
        s4 += p[(size_t)(s + 4) * 65536];
        s5 += p[(size_t)(s + 5) * 65536];
        s6 += p[(size_t)(s + 6) * 65536];
        s7 += p[(size_t)(s + 7) * 65536];
    }
    float sv = (((s0 + s1) + (s2 + s3)) + ((s4 + s5) + (s6 + s7))) * scale;
    svl[d * 33 + b] = sv;
    __syncthreads();
    if (t < 32) {   // t = b
        float n2 = 0.0f;
        #pragma unroll
        for (int dd = 0; dd < 32; ++dd) {
            float vv = svl[dd * 33 + t];
            n2 += vv * vv;
        }
        float norm = sqrtf(n2);
        scl[t] = n2 / ((1.0f + n2) * (norm + 1e-8f));
    }
    __syncthreads();
    // output phase with remapped roles for coalescing: b2 = t>>5, d2 = t&31
    int b2 = t >> 5, d2 = t & 31;
    float v = scl[b2] * svl[d2 * 33 + b2];
    if (addprev) v += addprev[(size_t)o * 1024 + t];           // [o][b2][d2] coalesced
    if (out_bod)
        outv[((size_t)b2 * 64 + o) * 32 + d2] = v;             // [b][o][d] row-coalesced
    else
        outv[(size_t)o * 1024 + t] = v;                        // [o][b][d] coalesced
}

// ============================ LEGACY PATH (round-1, proven) =================

__global__ __launch_bounds__(256, 4) void pass0_k(
    const float* __restrict__ x, const float* __restrict__ w, float* __restrict__ S)
{
    __shared__ __align__(16) unsigned short lw[16 * 512];
    __shared__ __align__(16) unsigned short lx[512];

    const int t = threadIdx.x, lane = t & 63, wv = t >> 6;
    const int bx = blockIdx.x;
    const int ic = bx & 255, og = bx >> 8;
    const int o0 = og * 16;
    const int d = lane & 31, half = lane >> 5;

    f32x16 acc[4] = {};

    for (int i = ic * 8; i < ic * 8 + 8; ++i) {
        #pragma unroll
        for (int r = 0; r < 4; ++r) {
            int cidx = r * 256 + t;
            int ol = cidx >> 6, j8 = cidx & 63;
            const float* g = w + (size_t)(o0 + ol) * 1048576 + (size_t)i * 512 + j8 * 8;
            float4 a = *(const float4*)g;
            float4 b2 = *(const float4*)(g + 4);
            uint4 val = { pack2(a.x, a.y), pack2(a.z, a.w), pack2(b2.x, b2.y), pack2(b2.z, b2.w) };
            *reinterpret_cast<uint4*>(&lw[ol * 512 + j8 * 8]) = val;
        }
        if (t < 128) {
            int b = t >> 2, kq = t & 3;
            float4 a = *(const float4*)(x + ((size_t)b * IN_ + i) * ID_ + kq * 4);
            uint2 val = { pack2(a.x, a.y), pack2(a.z, a.w) };
            *reinterpret_cast<uint2*>(&lx[b * 16 + kq * 4]) = val;
        }
        __syncthreads();

        short8 afr = *reinterpret_cast<const short8*>(&lx[(lane & 31) * 16 + half * 8]);
        #pragma unroll
        for (int oi = 0; oi < 4; ++oi) {
            int ol = wv * 4 + oi;
            short8 bfr = *reinterpret_cast<const short8*>(&lw[ol * 512 + d * 16 + half * 8]);
            acc[oi] = __builtin_amdgcn_mfma_f32_32x32x16_bf16(afr, bfr, acc[oi], 0, 0, 0);
        }
        __syncthreads();
    }

    #pragma unroll
    for (int oi = 0; oi < 4; ++oi) {
        int o = o0 + wv * 4 + oi;
        #pragma unroll
        for (int r = 0; r < 16; ++r) {
            int b = (r & 3) + 8 * (r >> 2) + 4 * half;
            atomicAdd(&S[((size_t)b * ON_ + o) * OD_ + d], acc[oi][r]);
        }
    }
}

__global__ __launch_bounds__(512, 2) void pass_route_k(
    const float* __restrict__ x, const float* __restrict__ w,
    const float* __restrict__ vin, float* __restrict__ S)
{
    __shared__ __align__(16) unsigned short lw[64 * 512];
    __shared__ __align__(16) unsigned short lx[512];
    __shared__ float blds[B_ * ON_];
    __shared__ float clds[B_ * ON_];

    const int t = threadIdx.x, lane = t & 63, wv = t >> 6;
    const int ic = blockIdx.x;
    const int d = lane & 31, half = lane >> 5;

    f32x16 acc[8] = {};

    for (int i = ic * 8; i < ic * 8 + 8; ++i) {
        #pragma unroll
        for (int r = 0; r < 8; ++r) {
            int cidx = r * 512 + t;
            int ol = cidx >> 6, j8 = cidx & 63;
            const float* g = w + (size_t)ol * 1048576 + (size_t)i * 512 + j8 * 8;
            float4 a = *(const float4*)g;
            float4 b2 = *(const float4*)(g + 4);
            uint4 val = { pack2(a.x, a.y), pack2(a.z, a.w), pack2(b2.x, b2.y), pack2(b2.z, b2.w) };
            *reinterpret_cast<uint4*>(&lw[ol * 512 + j8 * 8]) = val;
        }
        if (t < 128) {
            int b = t >> 2, kq = t & 3;
            float4 a = *(const float4*)(x + ((size_t)b * IN_ + i) * ID_ + kq * 4);
            uint2 val = { pack2(a.x, a.y), pack2(a.z, a.w) };
            *reinterpret_cast<uint2*>(&lx[b * 16 + kq * 4]) = val;
        }
        __syncthreads();

        short8 afr = *reinterpret_cast<const short8*>(&lx[(lane & 31) * 16 + half * 8]);
        short8 bfr[8];

        #pragma unroll
        for (int oi = 0; oi < 8; ++oi) {
            int o = wv * 8 + oi;
            bfr[oi] = *reinterpret_cast<const short8*>(&lw[o * 512 + d * 16 + half * 8]);
            f32x16 z = {};
            f32x16 C = __builtin_amdgcn_mfma_f32_32x32x16_bf16(afr, bfr[oi], z, 0, 0, 0);
            float bvp[16];
            #pragma unroll
            for (int r = 0; r < 16; ++r) {
                int b = (r & 3) + 8 * (r >> 2) + 4 * half;
                float vv = vin[((size_t)o * B_ + b) * OD_ + d];
                bvp[r] = C[r] * vv;
            }
            #pragma unroll
            for (int m = 1; m <= 16; m <<= 1) {
                #pragma unroll
                for (int r = 0; r < 16; ++r)
                    bvp[r] += __shfl_xor(bvp[r], m, 32);
            }
            if ((lane & 31) == 0) {
                #pragma unroll
                for (int r = 0; r < 16; ++r) {
                    int b = (r & 3) + 8 * (r >> 2) + 4 * half;
                    blds[b * ON_ + o] = bvp[r];
                }
            }
        }
        __syncthreads();

        {
            int o = t & 63, bq = t >> 6;
            #pragma unroll
            for (int j = 0; j < 4; ++j) {
                int b = bq + 8 * j;
                float v = blds[b * ON_ + o];
                float m = v;
                #pragma unroll
                for (int mm = 1; mm <= 32; mm <<= 1) m = fmaxf(m, __shfl_xor(m, mm, 64));
                float e = __expf(v - m);
                float ssum = e;
                #pragma unroll
                for (int mm = 1; mm <= 32; mm <<= 1) ssum += __shfl_xor(ssum, mm, 64);
                clds[b * ON_ + o] = e / ssum;
            }
        }
        __syncthreads();

        #pragma unroll
        for (int oi = 0; oi < 8; ++oi) {
            int o = wv * 8 + oi;
            f32x16 z = {};
            f32x16 C = __builtin_amdgcn_mfma_f32_32x32x16_bf16(afr, bfr[oi], z, 0, 0, 0);
            #pragma unroll
            for (int r = 0; r < 16; ++r) {
                int b = (r & 3) + 8 * (r >> 2) + 4 * half;
                acc[oi][r] += clds[b * ON_ + o] * C[r];
            }
        }
        __syncthreads();
    }

    #pragma unroll
    for (int oi = 0; oi < 8; ++oi) {
        int o = wv * 8 + oi;
        #pragma unroll
        for (int r = 0; r < 16; ++r) {
            int b = (r & 3) + 8 * (r >> 2) + 4 * half;
            atomicAdd(&S[((size_t)b * ON_ + o) * OD_ + d], acc[oi][r]);
        }
    }
}

__global__ __launch_bounds__(256) void squash_k(
    const float* __restrict__ S, const float* __restrict__ addprev,
    float* __restrict__ out, float scale, int out_bod)
{
    int t = threadIdx.x;
    int row = blockIdx.x * 8 + (t >> 5);
    int d = t & 31;
    int b = row >> 6, o = row & 63;
    float s = S[(size_t)row * OD_ + d] * scale;
    float n2 = s * s;
    #pragma unroll
    for (int mm = 1; mm <= 16; mm <<= 1) n2 += __shfl_xor(n2, mm, 32);
    float norm = sqrtf(n2);
    float sc = n2 / ((1.0f + n2) * (norm + 1e-8f));
    float v = sc * s;
    if (addprev) v += addprev[((size_t)o * B_ + b) * OD_ + d];
    if (out_bod)
        out[((size_t)b * ON_ + o) * OD_ + d] = v;
    else
        out[((size_t)o * B_ + b) * OD_ + d] = v;
}

// ============================ LAUNCHER ======================================

extern "C" void kernel_launch(void* const* d_in, const int* in_sizes, int n_in,
                              void* d_out, int out_size, void* d_ws, size_t ws_size,
                              hipStream_t stream) {
    (void)in_sizes; (void)n_in; (void)out_size;
    const float* x = (const float*)d_in[0];
    const float* w = (const float*)d_in[1];
    float* out = (float*)d_out;

    const size_t WBF_B  = 134217728;   // 64*2048*1024
    const size_t XBF_B  = 2097152;     // 2048*1024
    const size_t PART_B = 16777216;    // 64*65536*4
    const size_t L_B    = 16777216;    // 2048*2048*4
    const size_t MS_B   = 524288;      // 2048*32*8
    const size_t V_B    = 262144;
    const size_t NEED   = WBF_B + XBF_B + PART_B + L_B + MS_B + 2 * V_B;

    if (ws_size >= NEED) {
        uint8_t* wsb = (uint8_t*)d_ws;
        uint4*  wbf  = (uint4*)wsb;
        uint4*  xbf  = (uint4*)(wsb + WBF_B);
        float*  part = (float*)(wsb + WBF_B + XBF_B);
        float*  Lg   = (float*)(wsb + WBF_B + XBF_B + PART_B);
        float2* ms   = (float2*)(wsb + WBF_B + XBF_B + PART_B + L_B);
        float*  v0   = (float*)(wsb + WBF_B + XBF_B + PART_B + L_B + MS_B);
        float*  vsum = (float*)(wsb + WBF_B + XBF_B + PART_B + L_B + MS_B + V_B);

        xconv_k<<<512, 256, 0, stream>>>(x, xbf);
        pass0_k2<<<1024, 256, 0, stream>>>(w, xbf, wbf, part);
        reduce_squash_fused_k<<<64, 1024, 0, stream>>>(part, 1.0f / 64.0f, nullptr, v0, 0);

        logits_raw_k<<<4096, 256, 0, stream>>>(wbf, xbf, v0, Lg);
        msum_k<<<512, 256, 0, stream>>>(Lg, ms);
        accum_k<<<1024, 256, 0, stream>>>(wbf, xbf, Lg, ms, part);
        reduce_squash_fused_k<<<64, 1024, 0, stream>>>(part, 1.0f, v0, vsum, 0);

        logits_raw_k<<<4096, 256, 0, stream>>>(wbf, xbf, vsum, Lg);
        msum_k<<<512, 256, 0, stream>>>(Lg, ms);
        accum_k<<<1024, 256, 0, stream>>>(wbf, xbf, Lg, ms, part);
        reduce_squash_fused_k<<<64, 1024, 0, stream>>>(part, 1.0f, nullptr, out, 1);
    } else {
        // legacy (round-1) path — needs only 768 KB of ws
        float* S    = (float*)d_ws;
        float* v0   = S + 65536;
        float* vsum = v0 + 65536;
        const size_t Sbytes = (size_t)65536 * sizeof(float);

        hipMemsetAsync(S, 0, Sbytes, stream);
        pass0_k<<<1024, 256, 0, stream>>>(x, w, S);
        squash_k<<<256, 256, 0, stream>>>(S, nullptr, v0, 1.0f / 64.0f, 0);

        hipMemsetAsync(S, 0, Sbytes, stream);
        pass_route_k<<<256, 512, 0, stream>>>(x, w, v0, S);
        squash_k<<<256, 256, 0, stream>>>(S, v0, vsum, 1.0f, 0);

        hipMemsetAsync(S, 0, Sbytes, stream);
        pass_route_k<<<256, 512, 0, stream>>>(x, w, vsum, S);
        squash_k<<<256, 256, 0, stream>>>(S, nullptr, out, 1.0f, 1);
    }
}